// Round 1
// baseline (183.382 us; speedup 1.0000x reference)
//
#include <hip/hip_runtime.h>
#include <stdint.h>

// Problem constants
// B=16, S=8192, DIM=128, H=4, KV=2, D=64
// tokens = 131072; output [16, 16384, 128] fp32
//
// Refactor: per token t, Y[896] = W' x_t + bias where
//   Y[0:256)    = q   (reshaped-head order: channel ch -> Wq[ch&3][ch>>2][:])
//   Y[256:384)  = k   (channel i=ch-256 -> Wk[i&1][i>>1][:])
//   Y[384:896)  = vproj: ch-384 = kv*256 + p*128 + j,
//                 W'[ch][c] = sum_d Wo[j][p*64+d] * Wv[(kv*64+d)&1][(kv*64+d)>>1][c]
// Epilogue: qmean[d] = 0.25*sum_h Y[h*64+d]
//           attn[h][kv] = 0.125 * sum_d Y[h*64+d]*Y[256+kv*64+d]*qmean[d]
//           out[b,2s+r,j] = sum_{kv,p} attn[2r+p][kv] * Y[384+kv*256+p*128+j]

using short8 = __attribute__((ext_vector_type(8))) short;
using f32x4  = __attribute__((ext_vector_type(4))) float;

constexpr int YSTR = 904;   // LDS Y row stride (bf16 elems), padded (896+8)
constexpr int XSTR = 136;   // LDS x-stage row stride (bf16 elems), padded (128+8)

__device__ __forceinline__ unsigned short f2bf(float f) {
    unsigned int u = __float_as_uint(f);
    u += 0x7FFFu + ((u >> 16) & 1u);          // round-to-nearest-even
    return (unsigned short)(u >> 16);
}
__device__ __forceinline__ float bf2f(short h) {
    return __uint_as_float(((unsigned int)(unsigned short)h) << 16);
}

// ---------------- prep: build W' (bf16 [896][128]) and bias (fp32 [896]) ----------------
__global__ void prep_weights(const float* __restrict__ Wq, const float* __restrict__ bq,
                             const float* __restrict__ Wk, const float* __restrict__ bk,
                             const float* __restrict__ Wv, const float* __restrict__ bv,
                             const float* __restrict__ Wo,
                             unsigned short* __restrict__ Wp, float* __restrict__ bias)
{
    const int ch = blockIdx.x;      // 0..895
    const int c  = threadIdx.x;     // 0..127
    float w, b;
    if (ch < 256) {
        const int hh = ch & 3, dd = ch >> 2;
        w = Wq[(hh * 64 + dd) * 128 + c];
        b = bq[hh * 64 + dd];
    } else if (ch < 384) {
        const int i = ch - 256;
        const int kvh = i & 1, dd = i >> 1;
        w = Wk[(kvh * 64 + dd) * 128 + c];
        b = bk[kvh * 64 + dd];
    } else {
        const int i  = ch - 384;
        const int kv = i >> 8, p = (i >> 7) & 1, j = i & 127;
        float acc = 0.f, bacc = 0.f;
        #pragma unroll 8
        for (int d = 0; d < 64; ++d) {
            const int idx = kv * 64 + d;
            const int kvh = idx & 1, dd = idx >> 1;
            const float wo = Wo[j * 128 + p * 64 + d];
            acc  += wo * Wv[(kvh * 64 + dd) * 128 + c];
            bacc += wo * bv[kvh * 64 + dd];
        }
        w = acc; b = bacc;
    }
    Wp[ch * 128 + c] = f2bf(w);
    if (c == 0) bias[ch] = b;
}

// ---------------- fused main kernel ----------------
// grid 2048, block 512 (8 waves: 2 in M x 4 in N). 64 tokens/block, all 896 channels.
__global__ __launch_bounds__(512, 2)
void fused_attn_kernel(const float* __restrict__ x,
                       const unsigned short* __restrict__ Wp,
                       const float* __restrict__ bias,
                       float* __restrict__ out)
{
    __shared__ __align__(16) unsigned short lds[64 * YSTR];   // 115712 B

    const int tid = threadIdx.x;
    const int l   = tid & 63;
    const int wv  = tid >> 6;   // wave 0..7
    const int wm  = wv >> 2;    // 0..1 : token half (32 rows)
    const int wn  = wv & 3;     // 0..3 : channel quarter (224 ch)
    const int g0  = blockIdx.x * 64;

    // ---- stage x tile (64x128 fp32) -> LDS bf16, padded stride ----
    {
        const float4* xp = (const float4*)(x + (size_t)g0 * 128) + (size_t)tid * 4;
        float4 v0 = xp[0], v1 = xp[1], v2 = xp[2], v3 = xp[3];
        const int row = tid >> 3, col = (tid & 7) * 16;
        short8 s0, s1;
        s0[0]=(short)f2bf(v0.x); s0[1]=(short)f2bf(v0.y); s0[2]=(short)f2bf(v0.z); s0[3]=(short)f2bf(v0.w);
        s0[4]=(short)f2bf(v1.x); s0[5]=(short)f2bf(v1.y); s0[6]=(short)f2bf(v1.z); s0[7]=(short)f2bf(v1.w);
        s1[0]=(short)f2bf(v2.x); s1[1]=(short)f2bf(v2.y); s1[2]=(short)f2bf(v2.z); s1[3]=(short)f2bf(v2.w);
        s1[4]=(short)f2bf(v3.x); s1[5]=(short)f2bf(v3.y); s1[6]=(short)f2bf(v3.z); s1[7]=(short)f2bf(v3.w);
        *(short8*)&lds[row * XSTR + col]     = s0;
        *(short8*)&lds[row * XSTR + col + 8] = s1;
    }
    __syncthreads();

    // ---- MFMA: acc[2 Mfrags][14 Nfrags], 16x16x32 bf16, K=128 in 4 steps ----
    f32x4 acc[2][14];
    #pragma unroll
    for (int mf = 0; mf < 2; ++mf)
        #pragma unroll
        for (int nf = 0; nf < 14; ++nf)
            acc[mf][nf] = (f32x4){0.f, 0.f, 0.f, 0.f};

    const int cb = wn * 224;
    const int lr = l & 15, lg = l >> 4;

    #pragma unroll
    for (int ks = 0; ks < 4; ++ks) {
        const int k0 = ks * 32 + lg * 8;
        short8 a0 = *(const short8*)&lds[(wm * 32 +  0 + lr) * XSTR + k0];
        short8 a1 = *(const short8*)&lds[(wm * 32 + 16 + lr) * XSTR + k0];
        const unsigned short* wp = Wp + (size_t)(cb + lr) * 128 + k0;
        #pragma unroll
        for (int nf = 0; nf < 14; ++nf) {
            short8 bfr = *(const short8*)(wp + (size_t)nf * 16 * 128);
            acc[0][nf] = __builtin_amdgcn_mfma_f32_16x16x32_bf16(a0, bfr, acc[0][nf], 0, 0, 0);
            acc[1][nf] = __builtin_amdgcn_mfma_f32_16x16x32_bf16(a1, bfr, acc[1][nf], 0, 0, 0);
        }
    }
    __syncthreads();   // everyone done reading x-area of LDS before Y-dump overwrites it

    // ---- dump Y = acc + bias to LDS (bf16), layout [64 tokens][904] ----
    #pragma unroll
    for (int nf = 0; nf < 14; ++nf) {
        const int ch = cb + nf * 16 + lr;
        const float bv_ = bias[ch];
        #pragma unroll
        for (int mf = 0; mf < 2; ++mf) {
            const int row = wm * 32 + mf * 16 + lg * 4;
            #pragma unroll
            for (int r = 0; r < 4; ++r)
                lds[(row + r) * YSTR + ch] = f2bf(acc[mf][nf][r] + bv_);
        }
    }
    __syncthreads();

    // ---- epilogue: 8 lanes per token ----
    const int tk = tid >> 3, sub = tid & 7;
    const unsigned short* Yr = &lds[tk * YSTR];

    float pa00=0,pa01=0,pa10=0,pa11=0,pa20=0,pa21=0,pa30=0,pa31=0;
    {
        const int d0 = sub * 8;
        short8 q0 = *(const short8*)&Yr[      d0];
        short8 q1 = *(const short8*)&Yr[ 64 + d0];
        short8 q2 = *(const short8*)&Yr[128 + d0];
        short8 q3 = *(const short8*)&Yr[192 + d0];
        short8 k0 = *(const short8*)&Yr[256 + d0];
        short8 k1 = *(const short8*)&Yr[320 + d0];
        #pragma unroll
        for (int i = 0; i < 8; ++i) {
            const float a0 = bf2f(q0[i]), a1 = bf2f(q1[i]), a2 = bf2f(q2[i]), a3 = bf2f(q3[i]);
            const float qm = 0.25f * (a0 + a1 + a2 + a3);
            const float t0 = bf2f(k0[i]) * qm, t1 = bf2f(k1[i]) * qm;
            pa00 += a0 * t0; pa01 += a0 * t1;
            pa10 += a1 * t0; pa11 += a1 * t1;
            pa20 += a2 * t0; pa21 += a2 * t1;
            pa30 += a3 * t0; pa31 += a3 * t1;
        }
    }
    #pragma unroll
    for (int off = 1; off < 8; off <<= 1) {
        pa00 += __shfl_xor(pa00, off); pa01 += __shfl_xor(pa01, off);
        pa10 += __shfl_xor(pa10, off); pa11 += __shfl_xor(pa11, off);
        pa20 += __shfl_xor(pa20, off); pa21 += __shfl_xor(pa21, off);
        pa30 += __shfl_xor(pa30, off); pa31 += __shfl_xor(pa31, off);
    }
    const float sc = 0.125f;  // 1/sqrt(64)
    const float at00=pa00*sc, at01=pa01*sc, at10=pa10*sc, at11=pa11*sc;
    const float at20=pa20*sc, at21=pa21*sc, at30=pa30*sc, at31=pa31*sc;

    // vproj slices for this lane's 16 output columns
    const int j0 = sub * 16;
    float vp[4][16];   // kp = kv*2+p
    #pragma unroll
    for (int kp = 0; kp < 4; ++kp) {
        const unsigned short* vpp = &Yr[384 + kp * 128 + j0];
        short8 lo = *(const short8*)vpp;
        short8 hi = *(const short8*)(vpp + 8);
        #pragma unroll
        for (int i = 0; i < 8; ++i) { vp[kp][i] = bf2f(lo[i]); vp[kp][8 + i] = bf2f(hi[i]); }
    }

    const int g  = g0 + tk;
    const int bb = g >> 13, ss = g & 8191;
    float* orow = out + ((size_t)bb * 16384 + 2 * (size_t)ss) * 128 + j0;
    #pragma unroll
    for (int r = 0; r < 2; ++r) {
        const float a00 = r ? at20 : at00;   // attn[2r  ][0]
        const float a01 = r ? at30 : at10;   // attn[2r+1][0]
        const float a10 = r ? at21 : at01;   // attn[2r  ][1]
        const float a11 = r ? at31 : at11;   // attn[2r+1][1]
        float4* dst = (float4*)(orow + (size_t)r * 128);
        #pragma unroll
        for (int q = 0; q < 4; ++q) {
            float4 ov;
            ov.x = a00*vp[0][4*q+0] + a01*vp[1][4*q+0] + a10*vp[2][4*q+0] + a11*vp[3][4*q+0];
            ov.y = a00*vp[0][4*q+1] + a01*vp[1][4*q+1] + a10*vp[2][4*q+1] + a11*vp[3][4*q+1];
            ov.z = a00*vp[0][4*q+2] + a01*vp[1][4*q+2] + a10*vp[2][4*q+2] + a11*vp[3][4*q+2];
            ov.w = a00*vp[0][4*q+3] + a01*vp[1][4*q+3] + a10*vp[2][4*q+3] + a11*vp[3][4*q+3];
            dst[q] = ov;
        }
    }
}

extern "C" void kernel_launch(void* const* d_in, const int* in_sizes, int n_in,
                              void* d_out, int out_size, void* d_ws, size_t ws_size,
                              hipStream_t stream)
{
    (void)in_sizes; (void)n_in; (void)out_size; (void)ws_size;
    const float* x  = (const float*)d_in[0];
    const float* Wq = (const float*)d_in[1];
    const float* bq = (const float*)d_in[2];
    const float* Wk = (const float*)d_in[3];
    const float* bk = (const float*)d_in[4];
    const float* Wv = (const float*)d_in[5];
    const float* bv = (const float*)d_in[6];
    const float* Wo = (const float*)d_in[7];

    unsigned short* Wp   = (unsigned short*)d_ws;                    // 896*128 bf16 = 229376 B
    float*          bias = (float*)((char*)d_ws + 896 * 128 * 2);    // 896 fp32

    prep_weights<<<896, 128, 0, stream>>>(Wq, bq, Wk, bk, Wv, bv, Wo, Wp, bias);
    fused_attn_kernel<<<2048, 512, 0, stream>>>(x, Wp, bias, (float*)d_out);
}